// Round 2
// baseline (168.215 us; speedup 1.0000x reference)
//
#include <hip/hip_runtime.h>
#include <hip/hip_bf16.h>
#include <stdint.h>

#define NROW 8192
#define DIM  256
#define BK   32
#define KSPLIT 4
#define NT   64   // (8192/KSPLIT)/BK

typedef float  f32x4  __attribute__((ext_vector_type(4)));
typedef __bf16 bf16x8 __attribute__((ext_vector_type(8)));
typedef unsigned short ushort8 __attribute__((ext_vector_type(8)));

// round-to-nearest-even f32 -> bf16 (bit pattern)
__device__ __forceinline__ unsigned short f2bf(float f) {
  union { float f; uint32_t u; } v; v.f = f;
  uint32_t u = v.u;
  return (unsigned short)((u + 0x7FFFu + ((u >> 16) & 1u)) >> 16);
}

__device__ __forceinline__ void gload_lds16(const void* gsrc, void* ldsdst) {
  __builtin_amdgcn_global_load_lds(
      (const __attribute__((address_space(1))) uint32_t*)gsrc,
      (__attribute__((address_space(3))) uint32_t*)ldsdst, 16, 0, 0);
}

// ---------------- K0: d = rsqrt(rowsum(g)) ----------------
__global__ __launch_bounds__(256) void k_rowsum(const float* __restrict__ g,
                                                float* __restrict__ d) {
  int r = blockIdx.x;
  const float4* row = (const float4*)(g + (size_t)r * NROW);
  float s = 0.f;
#pragma unroll
  for (int i = 0; i < 8; ++i) {
    float4 v = row[threadIdx.x + i * 256];
    s += (v.x + v.y) + (v.z + v.w);
  }
#pragma unroll
  for (int off = 32; off > 0; off >>= 1) s += __shfl_down(s, off, 64);
  __shared__ float red[4];
  int lane = threadIdx.x & 63, w = threadIdx.x >> 6;
  if (lane == 0) red[w] = s;
  __syncthreads();
  if (threadIdx.x == 0) {
    float t = (red[0] + red[1]) + (red[2] + red[3]);
    d[r] = rsqrtf(t);
  }
}

// ---------------- K1: X[kb][n][kin] = bf16(d_j * h[j][n]), j = kb*32+kin ----------------
__global__ __launch_bounds__(256) void k_buildx(const float* __restrict__ h,
                                                const float* __restrict__ d,
                                                unsigned short* __restrict__ X) {
  int kb = blockIdx.x;
  int j0 = kb * 32;
  __shared__ float tile[32][DIM];   // unpadded: f4 writes stay 16B-aligned;
  __shared__ float dl[32];          // column reads are 2-way bank alias (free)
  int tid = threadIdx.x;
  // full 32x256 f32 tile: 8192 floats = 2048 float4 = 8 per thread
#pragma unroll
  for (int i = 0; i < 8; ++i) {
    int e = i * 256 + tid;
    int rr = e >> 6, c4 = e & 63;   // 32 rows x 64 float4-cols
    *(float4*)&tile[rr][c4 * 4] =
        *(const float4*)(h + (size_t)(j0 + rr) * DIM + c4 * 4);
  }
  if (tid < 32) dl[tid] = d[j0 + tid];
  __syncthreads();
  unsigned short outv[32];
#pragma unroll
  for (int kin = 0; kin < 32; ++kin)
    outv[kin] = f2bf(tile[kin][tid] * dl[kin]);
  uint4* dst = (uint4*)(X + (size_t)kb * 8192 + tid * 32);
  const uint4* src = (const uint4*)outv;
  dst[0] = src[0]; dst[1] = src[1]; dst[2] = src[2]; dst[3] = src[3];
}

// ---------------- K2: z += g_tile @ X  (bf16 MFMA, split-K, atomics into z) ----------------
__global__ __launch_bounds__(256, 4) void k_gemm1(const float* __restrict__ g,
                                                  const unsigned short* __restrict__ X,
                                                  float* __restrict__ z) {
  int bid = blockIdx.x;
  int mtile = bid >> 2, ks = bid & 3;
  int m0 = mtile * 32;
  int kbase = ks * 2048;

  __shared__ float          A[2][32][BK];    // fp32 g tile, 2 x 4KB
  __shared__ unsigned short B[2][DIM][BK];   // bf16 X tile, 2 x 16KB

  int tid = threadIdx.x;
  int lane = tid & 63, w = tid >> 6;
  int frow = lane & 15;
  int kgrp = lane >> 4;

  f32x4 acc[2][4];
#pragma unroll
  for (int i = 0; i < 2; ++i)
#pragma unroll
    for (int j = 0; j < 4; ++j) acc[i][j] = (f32x4)0.f;

  auto stage = [&](int buf, int t) {
    int k0 = kbase + t * BK;
    {
      const void* gsrc = g + (size_t)(m0 + (tid >> 3)) * NROW + k0 + (tid & 7) * 4;
      void* dst = (char*)&A[buf][0][0] + w * 1024;
      gload_lds16(gsrc, dst);
    }
    const char* chunk = (const char*)(X + (size_t)(k0 >> 5) * 8192);
#pragma unroll
    for (int q = 0; q < 4; ++q) {
      const void* gsrc = chunk + q * 4096 + tid * 16;
      void* dst = (char*)&B[buf][0][0] + q * 4096 + w * 1024;
      gload_lds16(gsrc, dst);
    }
  };

  stage(0, 0);
  asm volatile("s_waitcnt vmcnt(0)" ::: "memory");
  __syncthreads();

#pragma unroll 2
  for (int t = 0; t < NT; ++t) {
    int cur = t & 1;
    if (t + 1 < NT) stage(cur ^ 1, t + 1);

    bf16x8 bfr[4];
#pragma unroll
    for (int nf = 0; nf < 4; ++nf) {
      const ushort8* p = (const ushort8*)&B[cur][w * 64 + nf * 16 + frow][kgrp * 8];
      bfr[nf] = __builtin_bit_cast(bf16x8, *p);
    }
#pragma unroll
    for (int mf = 0; mf < 2; ++mf) {
      const float4* pa = (const float4*)&A[cur][mf * 16 + frow][kgrp * 8];
      float4 a0 = pa[0], a1 = pa[1];
      ushort8 au;
      au[0] = f2bf(a0.x); au[1] = f2bf(a0.y); au[2] = f2bf(a0.z); au[3] = f2bf(a0.w);
      au[4] = f2bf(a1.x); au[5] = f2bf(a1.y); au[6] = f2bf(a1.z); au[7] = f2bf(a1.w);
      bf16x8 af = __builtin_bit_cast(bf16x8, au);
#pragma unroll
      for (int nf = 0; nf < 4; ++nf)
        acc[mf][nf] = __builtin_amdgcn_mfma_f32_16x16x32_bf16(af, bfr[nf], acc[mf][nf], 0, 0, 0);
    }
    asm volatile("s_waitcnt vmcnt(0)" ::: "memory");
    __syncthreads();
  }

#pragma unroll
  for (int mf = 0; mf < 2; ++mf)
#pragma unroll
    for (int nf = 0; nf < 4; ++nf)
#pragma unroll
      for (int r = 0; r < 4; ++r) {
        int row = m0 + mf * 16 + kgrp * 4 + r;
        int col = w * 64 + nf * 16 + frow;
        unsafeAtomicAdd(&z[(size_t)row * DIM + col], acc[mf][nf][r]);
      }
}

// ---------------- K3: out = relu((h + d*z) @ W^T + b), in-place on z (=d_out) ----------------
__global__ __launch_bounds__(256) void k_out(float* __restrict__ zout,
                                             const float* __restrict__ h,
                                             const float* __restrict__ d,
                                             const float* __restrict__ Wm,
                                             const float* __restrict__ bias) {
  int m0 = blockIdx.x * 32;
  __shared__ unsigned short agg[32][DIM + 8];  // row stride 528B: 16B-aligned, 2-way banks
  int tid = threadIdx.x;
#pragma unroll
  for (int i = 0; i < 8; ++i) {
    int e = i * 256 + tid;
    int rr = e >> 6, c4 = e & 63;
    size_t off = (size_t)(m0 + rr) * DIM + c4 * 4;
    float4 zv = *(const float4*)(zout + off);
    float4 hv = *(const float4*)(h + off);
    float dr = d[m0 + rr];
    agg[rr][c4 * 4 + 0] = f2bf(hv.x + dr * zv.x);
    agg[rr][c4 * 4 + 1] = f2bf(hv.y + dr * zv.y);
    agg[rr][c4 * 4 + 2] = f2bf(hv.z + dr * zv.z);
    agg[rr][c4 * 4 + 3] = f2bf(hv.w + dr * zv.w);
  }
  __syncthreads();

  int lane = tid & 63, w = tid >> 6;
  int frow = lane & 15, kgrp = lane >> 4;
  f32x4 acc[2][4];
#pragma unroll
  for (int i = 0; i < 2; ++i)
#pragma unroll
    for (int j = 0; j < 4; ++j) acc[i][j] = (f32x4)0.f;

#pragma unroll
  for (int t = 0; t < 8; ++t) {
    int k0 = t * 32;
    bf16x8 af[2];
#pragma unroll
    for (int mf = 0; mf < 2; ++mf) {
      const ushort8* p = (const ushort8*)&agg[mf * 16 + frow][k0 + kgrp * 8];
      af[mf] = __builtin_bit_cast(bf16x8, *p);
    }
#pragma unroll
    for (int nf = 0; nf < 4; ++nf) {
      int c = w * 64 + nf * 16 + frow;
      const float4* pw = (const float4*)(Wm + (size_t)c * DIM + k0 + kgrp * 8);
      float4 w0 = pw[0], w1 = pw[1];
      ushort8 bu;
      bu[0] = f2bf(w0.x); bu[1] = f2bf(w0.y); bu[2] = f2bf(w0.z); bu[3] = f2bf(w0.w);
      bu[4] = f2bf(w1.x); bu[5] = f2bf(w1.y); bu[6] = f2bf(w1.z); bu[7] = f2bf(w1.w);
      bf16x8 bfr = __builtin_bit_cast(bf16x8, bu);
#pragma unroll
      for (int mf = 0; mf < 2; ++mf)
        acc[mf][nf] = __builtin_amdgcn_mfma_f32_16x16x32_bf16(af[mf], bfr, acc[mf][nf], 0, 0, 0);
    }
  }

#pragma unroll
  for (int mf = 0; mf < 2; ++mf)
#pragma unroll
    for (int nf = 0; nf < 4; ++nf)
#pragma unroll
      for (int r = 0; r < 4; ++r) {
        int row = m0 + mf * 16 + kgrp * 4 + r;
        int col = w * 64 + nf * 16 + frow;
        float v = acc[mf][nf][r] + bias[col];
        zout[(size_t)row * DIM + col] = fmaxf(v, 0.f);
      }
}

extern "C" void kernel_launch(void* const* d_in, const int* in_sizes, int n_in,
                              void* d_out, int out_size, void* d_ws, size_t ws_size,
                              hipStream_t stream) {
  const float* g    = (const float*)d_in[0];
  const float* h    = (const float*)d_in[1];
  const float* Wm   = (const float*)d_in[2];
  const float* bias = (const float*)d_in[3];
  float* out = (float*)d_out;

  float* dvec = (float*)d_ws;                                       // 8192 f32 = 32KB
  unsigned short* X = (unsigned short*)((char*)d_ws + 8192 * 4);    // 4MB bf16, [kb][n][kin]

  hipMemsetAsync(d_out, 0, (size_t)NROW * DIM * sizeof(float), stream);
  k_rowsum<<<NROW, 256, 0, stream>>>(g, dvec);
  k_buildx<<<NROW / 32, 256, 0, stream>>>(h, dvec, X);
  k_gemm1<<<(NROW / 32) * KSPLIT, 256, 0, stream>>>(g, X, out);
  k_out<<<NROW / 32, 256, 0, stream>>>(out, h, dvec, Wm, bias);
}